// Round 16
// baseline (479.752 us; speedup 1.0000x reference)
//
#include <hip/hip_runtime.h>
#include <hip/hip_bf16.h>

#define BB 512
#define SS 1024
#define NI 20
#define HH 64
#define NG 256   // 4*H
#define MB4 4    // batch-dirs per block (1 cell per lane)
#define PAD 80   // h-row stride in f16
#define TSTR 257 // x-table row stride (floats)

typedef unsigned short u16;
typedef unsigned int u32;
typedef unsigned long long u64;
typedef _Float16 f16;
typedef f16 f16x8 __attribute__((ext_vector_type(8)));
typedef float f32x4 __attribute__((ext_vector_type(4)));

#define LOG2E 1.4426950408889634f

__device__ __forceinline__ float bf2f(u16 b) { return __uint_as_float(((u32)b) << 16); }
// mode==1: data is bf16; mode==0: data is fp32
__device__ __forceinline__ float ldw(const void* p, int idx, int mode) {
  return mode ? bf2f(((const u16*)p)[idx]) : ((const float*)p)[idx];
}
__device__ __forceinline__ float frcp(float x) { return __builtin_amdgcn_rcpf(x); }
__device__ __forceinline__ float fexp2(float x) { return __builtin_amdgcn_exp2f(x); }

// Pade(7,6) tanh (continued-fraction truncation): err <= 2e-4 on [-4,4], clamped.
// Replaces serial exp2 chains with parallel fma chains -> shorter critical path.
__device__ __forceinline__ float tpade(float x) {
  x = fminf(4.f, fmaxf(-4.f, x));
  float t = x * x;
  float pn = fmaf(21.f, t, 1260.f);
  pn = fmaf(pn, t, 10395.f);
  float pd = t + 210.f;
  pd = fmaf(pd, t, 4725.f);
  pd = fmaf(pd, t, 10395.f);
  return (x * pn) * frcp(pd);
}

// ---- BiLSTM (r13/r14-verified structure; activation now Pade-poly) ----
// 256 blocks x 256 thr, 1 wave/SIMD (r4/r8/r15: with chains==SIMDs, added TLP
// always pays in redundancy/issue-sum; the lever is the per-step critical path).
// Block = (dir, 4 batches). Wave w owns units 16w..16w+15, 4 gate types in-lane;
// lane (l,q) = cell (batch q, unit 16w+l); A-rows dup h[l>>2] 4x. x-projection
// rides MFMA C-init from LDS table (prefetched 1 step ahead) -> 8 MFMA/step in
// ONE serial C-chain per gate type (r10: C-forwarding free; split regressed).
// Weights prescaled: i,f,o rows by 0.5 (sig(x)=0.5+0.5*tanh(x/2)), g by 1.0.
// NO epilogue in this kernel (r11/r12: fused epilogue inflates VGPR 52->104+,
// degrades loop pipelining ~70-95 us).
__global__ __launch_bounds__(256)
void lstm_kernel(const void* in1,
                 const void* Wih_f, const void* Whh_f, const void* b_f,
                 const void* Wih_b, const void* Whh_b, const void* b_b,
                 short* toks_g, int* lens, float* hout) {
  int bx = blockIdx.x;          // 0..255
  int dir = bx >> 7;
  int b0 = (bx & 127) * MB4;
  int t = threadIdx.x;
  int w = t >> 6, lane = t & 63, l = lane & 15, q = lane >> 4;
  int bsel = l >> 2;            // batch whose h this lane's A-row carries

  __shared__ __align__(16) float table[21 * TSTR];  // 21.6 KB; doubles as extract staging
  __shared__ __align__(16) f16 hbuf[2][MB4][PAD];
  __shared__ short tok_s[SS * MB4];                 // [pos][m], stores tok+1
  __shared__ u64 red[256];
  __shared__ int mode_sh;

  // ---- mode probe: b_f read as bf16; fp32 shows wild exponents ----
  if (t == 0) mode_sh = 1;
  __syncthreads();
  {
    float v = bf2f(((const u16*)b_f)[t]);
    if (!(fabsf(v) < 1000.0f)) atomicAnd(&mode_sh, 0);
  }
  __syncthreads();
  int mode = mode_sh;
  const void* Wih = dir ? Wih_b : Wih_f;
  const void* Whh = dir ? Whh_b : Whh_f;
  const void* bv  = dir ? b_b   : b_f;

  // ---- token extraction for this block's 4 batches (staged through `table` memory) ----
  u64 cnt = 0;  // packed 4x16-bit valid counts
  for (int m = 0; m < MB4; ++m) {
    if (mode) {
      u32* st = (u32*)table;
      for (int k0 = 0; k0 < 4; ++k0) {
        const u32* src = (const u32*)in1 + ((size_t)(b0 + m) * SS + k0 * 256) * 10;
#pragma unroll
        for (int i = 0; i < 10; ++i) st[t + i * 256] = src[t + i * 256];  // coalesced
        __syncthreads();
        const u32* row = st + t * 10;
        int tok = -1;
#pragma unroll
        for (int ww = 0; ww < 10; ++ww) {
          u32 u = row[ww];
          if (u & 0xFFFFu) tok = 2 * ww;
          if (u >> 16)     tok = 2 * ww + 1;
        }
        tok_s[(k0 * 256 + t) * MB4 + m] = (short)(tok + 1);
        if (dir == 0) toks_g[(size_t)(b0 + m) * SS + k0 * 256 + t] = (short)tok;
        cnt += (u64)(tok >= 0) << (16 * m);
        __syncthreads();
      }
    } else {
      float4* st = (float4*)table;
      for (int k0 = 0; k0 < 4; ++k0) {
        const float4* src = (const float4*)((const float*)in1 + ((size_t)(b0 + m) * SS + k0 * 256) * 20);
#pragma unroll
        for (int i = 0; i < 5; ++i) st[t + i * 256] = src[t + i * 256];  // coalesced 16B/lane
        __syncthreads();
        const float* row = (const float*)table + t * 20;
        int tok = -1;
#pragma unroll
        for (int ww = 0; ww < 20; ++ww)
          if (row[ww] != 0.f) tok = ww;
        tok_s[(k0 * 256 + t) * MB4 + m] = (short)(tok + 1);
        if (dir == 0) toks_g[(size_t)(b0 + m) * SS + k0 * 256 + t] = (short)tok;
        cnt += (u64)(tok >= 0) << (16 * m);
        __syncthreads();
      }
    }
  }
  // lens: packed u64 tree reduction (fwd blocks export)
  red[t] = cnt;
  __syncthreads();
  for (int stp = 128; stp > 0; stp >>= 1) {
    if (t < stp) red[t] += red[t + stp];
    __syncthreads();
  }
  if (dir == 0 && t < MB4)
    lens[b0 + t] = (int)((red[0] >> (16 * t)) & 0xFFFFull);
  __syncthreads();

  // ---- x-projection table: table[tok+1][g] = scl_g * (W_ih[g][tok] + b[g]); row 0 = bias ----
  for (int idx = t; idx < 21 * 256; idx += 256) {
    int r = idx >> 8, g = idx & 255;
    float scl = ((g >> 6) == 2) ? 1.f : 0.5f;   // g rows raw; i,f,o rows halved for tanh(x/2)
    float v = ldw(bv, g, mode);
    if (r > 0) v += ldw(Wih, g * NI + (r - 1), mode);
    table[r * TSTR + g] = scl * v;
  }
  // ---- W_hh B-fragments: n=lane&15 -> gate col (unit 16w+l, type tt), k=q*8+j ----
  f16x8 Bf[4][2];
#pragma unroll
  for (int tt = 0; tt < 4; ++tt) {
    float scl = (tt == 2) ? 1.f : 0.5f;
    int g = 64 * tt + 16 * w + l;
#pragma unroll
    for (int kc = 0; kc < 2; ++kc) {
      f16x8 v;
#pragma unroll
      for (int j = 0; j < 8; ++j)
        v[j] = (f16)(scl * ldw(Whh, g * HH + kc * 32 + q * 8 + j, mode));
      Bf[tt][kc] = v;
    }
  }
  for (int idx = t; idx < 2 * MB4 * PAD; idx += 256)
    ((f16*)hbuf)[idx] = (f16)0.f;
  __syncthreads();

  float c_st = 0.f, hlast = 0.f;
  int jj = 16 * w + l;
  int tbase = 16 * w + l;  // gate column offset within a table row

  // x-pipeline prologue: wx for s=0 (regs), tok for s=1 (reg)
  float wxc[4];
  {
    int pos0 = dir ? (SS - 1) : 0;
    int base = (int)tok_s[pos0 * MB4 + q] * TSTR + tbase;
    wxc[0] = table[base];       wxc[1] = table[base + 64];
    wxc[2] = table[base + 128]; wxc[3] = table[base + 192];
  }
  int tok1;
  {
    int pos1 = dir ? (SS - 2) : 1;
    tok1 = (int)tok_s[pos1 * MB4 + q];
  }

#pragma unroll 2
  for (int s = 0; s < SS; ++s) {
    int p = s & 1;
    // critical path: h fragments (A[m=l][k=q*8+j] = h[bsel][k], 4x dup rows)
    f16x8 a0 = *(const f16x8*)&hbuf[p][bsel][q * 8];
    f16x8 a1 = *(const f16x8*)&hbuf[p][bsel][32 + q * 8];
    // off-path: wx prefetch for s+1 (tok1 from pipeline), tok fetch for s+2
    float wxn[4];
    {
      int base = tok1 * TSTR + tbase;
      wxn[0] = table[base];       wxn[1] = table[base + 64];
      wxn[2] = table[base + 128]; wxn[3] = table[base + 192];
    }
    {
      int pos2 = (dir ? (SS - 3 - s) : (s + 2)) & (SS - 1);  // wrapped values unused
      tok1 = (int)tok_s[pos2 * MB4 + q];
    }

    // r9-verified serial C-chain: C-init = x-projection, 2-deep MFMA per gate type
    f32x4 acc[4];
#pragma unroll
    for (int tt = 0; tt < 4; ++tt) {
      f32x4 ci = {wxc[tt], wxc[tt], wxc[tt], wxc[tt]};
      acc[tt] = __builtin_amdgcn_mfma_f32_16x16x32_f16(a0, Bf[tt][0], ci, 0, 0, 0);
    }
#pragma unroll
    for (int tt = 0; tt < 4; ++tt)
      acc[tt] = __builtin_amdgcn_mfma_f32_16x16x32_f16(a1, Bf[tt][1], acc[tt], 0, 0, 0);

    // activation via Pade tanh (i,f,o accs arrive as x/2; g raw):
    //   sig(x)=0.5+0.5*tanh(x/2); cv = sig(f)c + sig(i)tanh(g); h = sig(o)tanh(cv)
    {
      float si = fmaf(0.5f, tpade(acc[0][0]), 0.5f);
      float sf = fmaf(0.5f, tpade(acc[1][0]), 0.5f);
      float tg = tpade(acc[2][0]);
      float so = fmaf(0.5f, tpade(acc[3][0]), 0.5f);
      float cv = fmaf(sf, c_st, si * tg);
      c_st = cv;
      float hv = so * tpade(cv);
      hlast = hv;
      hbuf[p ^ 1][q][jj] = (f16)hv;
    }
    __syncthreads();
    wxc[0] = wxn[0]; wxc[1] = wxn[1]; wxc[2] = wxn[2]; wxc[3] = wxn[3];
  }
  hout[(b0 + q) * 128 + dir * 64 + jj] = hlast;
}

// ---- head, latency-optimized (r14-verified, ~22 us): 512 blocks x 256 thr ----
__global__ __launch_bounds__(256)
void head_kernel(const void* conv1_w, const void* conv2_w, const void* conv2_b,
                 const void* fc1_w, const void* fc1_b,
                 const void* fc2_w, const void* fc2_b,
                 const void* bvec, const short* toks, const int* lens,
                 const float* hout, void* out) {
  int b = blockIdx.x;
  int t = threadIdx.x;  // 256 threads
  __shared__ float c1w[400];
  __shared__ short tok_s[SS];
  __shared__ float pav[3][80];
  __shared__ float avg[80];
  __shared__ float cpart[2][100];
  __shared__ float merged[228];
  __shared__ float fpart[4][64];
  __shared__ float fc1v[64];
  __shared__ float f2p[2][64];
  __shared__ int mode_sh;

  if (t == 0) mode_sh = 1;
  __syncthreads();
  {
    float v = bf2f(((const u16*)bvec)[t]);
    if (!(fabsf(v) < 1000.0f)) atomicAnd(&mode_sh, 0);
  }
  __syncthreads();
  int mode = mode_sh;

  for (int i = t; i < 400; i += 256) c1w[i] = ldw(conv1_w, i, mode);
  for (int s = t; s < SS; s += 256) tok_s[s] = toks[(size_t)b * SS + s];
  __syncthreads();

  int len = lens[b];
  int bw = len >> 2;
  // ragged 4-bin mean: 240 threads = 80 (k,cc) units x 3 segments; 4 independent
  // partial-sum chains per thread so the tok->c1w dependent LDS reads pipeline.
  if (t < 240) {
    int seg = t / 80;
    int u = t - seg * 80;
    int k = u / 20, cc = u % 20;
    int base = k * bw;
    int s0 = base + (seg * bw) / 3;
    int s1 = base + ((seg + 1) * bw) / 3;
    float p0 = 0.f, p1 = 0.f, p2 = 0.f, p3 = 0.f;
    int s = s0;
    for (; s + 4 <= s1; s += 4) {
      // faithful torch reshape: flat f = s*20+cc of the [20,1024] map
      int f0 = s * 20 + cc, f1 = f0 + 20, f2 = f0 + 40, f3 = f0 + 60;
      int tk0 = tok_s[f0 & 1023];
      int tk1 = tok_s[f1 & 1023];
      int tk2 = tok_s[f2 & 1023];
      int tk3 = tok_s[f3 & 1023];
      if (tk0 >= 0) p0 += c1w[(f0 >> 10) * 20 + tk0];
      if (tk1 >= 0) p1 += c1w[(f1 >> 10) * 20 + tk1];
      if (tk2 >= 0) p2 += c1w[(f2 >> 10) * 20 + tk2];
      if (tk3 >= 0) p3 += c1w[(f3 >> 10) * 20 + tk3];
    }
    for (; s < s1; ++s) {
      int f = s * 20 + cc;
      int tk = tok_s[f & 1023];
      if (tk >= 0) p0 += c1w[(f >> 10) * 20 + tk];
    }
    pav[seg][u] = (p0 + p1) + (p2 + p3);
  }
  __syncthreads();
  if (t < 80) avg[t] = (pav[0][t] + pav[1][t] + pav[2][t]) / (float)bw;
  __syncthreads();

  // conv2: 200 threads = 100 outputs x 2 K-halves of 40, unroll 8
  if (t < 200) {
    int half = t / 100, o = t - half * 100;
    float dot = 0.f;
    int q0 = half * 40;
#pragma unroll 8
    for (int q = q0; q < q0 + 40; ++q)
      dot = fmaf(avg[q], ldw(conv2_w, o * 80 + q, mode), dot);
    cpart[half][o] = dot;
  }
  if (t < 128) merged[t] = hout[b * 128 + t];  // [h_fw | h_bw]
  __syncthreads();
  if (t < 100) {
    float dot = cpart[0][t] + cpart[1][t] + ldw(conv2_b, t, mode);
    merged[128 + t] = dot > 0.f ? dot : 0.f;  // relu
  }
  __syncthreads();

  // fc1: 256 threads = 64 outputs x 4 K-chunks of 57, unroll 8
  {
    int o = t & 63, ch = t >> 6;
    float v = 0.f;
    int m0 = ch * 57;
#pragma unroll 8
    for (int m = m0; m < m0 + 57; ++m)
      v = fmaf(merged[m], ldw(fc1_w, o * 228 + m, mode), v);
    fpart[ch][o] = v;
  }
  __syncthreads();
  if (t < 64)
    fc1v[t] = fpart[0][t] + fpart[1][t] + fpart[2][t] + fpart[3][t] + ldw(fc1_b, t, mode);
  __syncthreads();

  // fc2: 128 threads compute products, tree-reduce
  if (t < 128) {
    int o = t >> 6, m = t & 63;
    f2p[o][m] = fc1v[m] * ldw(fc2_w, o * 64 + m, mode);
  }
  __syncthreads();
  for (int stp = 32; stp > 0; stp >>= 1) {
    if (t < 128) {
      int o = t >> 6, m = t & 63;
      if (m < stp) f2p[o][m] += f2p[o][m + stp];
    }
    __syncthreads();
  }
  if (t == 0) {
    float x0 = f2p[0][0] + ldw(fc2_b, 0, mode);
    float x1 = f2p[1][0] + ldw(fc2_b, 1, mode);
    float mx = fmaxf(x0, x1);
    float e0 = fexp2(LOG2E * (x0 - mx)), e1 = fexp2(LOG2E * (x1 - mx));
    float inv = frcp(e0 + e1);
    if (mode) {
      ((__hip_bfloat16*)out)[b * 2 + 0] = __float2bfloat16(e0 * inv);
      ((__hip_bfloat16*)out)[b * 2 + 1] = __float2bfloat16(e1 * inv);
    } else {
      ((float*)out)[b * 2 + 0] = e0 * inv;
      ((float*)out)[b * 2 + 1] = e1 * inv;
    }
  }
}

extern "C" void kernel_launch(void* const* d_in, const int* in_sizes, int n_in,
                              void* d_out, int out_size, void* d_ws, size_t ws_size,
                              hipStream_t stream) {
  (void)in_sizes; (void)n_in; (void)out_size; (void)ws_size;
  char* ws = (char*)d_ws;
  int*   lens = (int*)(ws + 256);                             // 2 KB
  short* toks = (short*)(ws + 256 + 2048);                    // 1 MB
  float* hout = (float*)(ws + 256 + 2048 + (size_t)BB * SS * sizeof(short)); // 256 KB

  lstm_kernel<<<256, 256, 0, stream>>>(d_in[0],
                                       d_in[1], d_in[2], d_in[3],
                                       d_in[4], d_in[5], d_in[6],
                                       toks, lens, hout);
  head_kernel<<<BB, 256, 0, stream>>>(d_in[7], d_in[8], d_in[9],
                                      d_in[10], d_in[11], d_in[12], d_in[13],
                                      d_in[3], toks, lens, hout, d_out);
}

// Round 17
// 391.006 us; speedup vs baseline: 1.2270x; 1.2270x over previous
//
#include <hip/hip_runtime.h>
#include <hip/hip_bf16.h>

#define BB 512
#define SS 1024
#define NI 20
#define HH 64
#define NG 256   // 4*H
#define MB4 4    // batch-dirs per block (1 cell per lane)
#define PAD 80   // h-row stride in f16

typedef unsigned short u16;
typedef unsigned int u32;
typedef unsigned long long u64;
typedef _Float16 f16;
typedef f16 f16x8 __attribute__((ext_vector_type(8)));
typedef float f32x4 __attribute__((ext_vector_type(4)));

#define LOG2E 1.4426950408889634f

__device__ __forceinline__ float bf2f(u16 b) { return __uint_as_float(((u32)b) << 16); }
// mode==1: data is bf16; mode==0: data is fp32
__device__ __forceinline__ float ldw(const void* p, int idx, int mode) {
  return mode ? bf2f(((const u16*)p)[idx]) : ((const float*)p)[idx];
}
__device__ __forceinline__ float frcp(float x) { return __builtin_amdgcn_rcpf(x); }
__device__ __forceinline__ float fexp2(float x) { return __builtin_amdgcn_exp2f(x); }

// ---- BiLSTM (r14 structure; x-table repacked for single-b128 wx prefetch) ----
// 256 blocks x 256 thr, 1 wave/SIMD (r4/r8/r15: with chains==SIMDs, extra TLP
// pays in redundancy/issue-sum; lever is the per-step critical path only).
// Block = (dir, 4 batches). Wave w owns units 16w..16w+15, 4 gate types in-lane;
// lane (l,q) = cell (batch q, unit 16w+l); A-rows dup h[l>>2] 4x. x-projection
// rides MFMA C-init from LDS table4[tok][unit][gate-type] -- the 4 per-step wx
// values are one aligned ds_read_b128 (r14 used 4 strided b32: 4x issue + the
// 5.5M bank conflicts). 8 MFMA/step in ONE serial C-chain per gate type (r10:
// C-forwarding free). Weights prescaled: i,f,o by -log2e, g by +2log2e
// (exp2-ready gates; trans-pipe activation -- r16: poly on VALU pipe regressed).
// NO epilogue (r11/r12: fused epilogue inflates VGPR 52->104+, kills pipelining).
__global__ __launch_bounds__(256)
void lstm_kernel(const void* in1,
                 const void* Wih_f, const void* Whh_f, const void* b_f,
                 const void* Wih_b, const void* Whh_b, const void* b_b,
                 short* toks_g, int* lens, float* hout) {
  int bx = blockIdx.x;          // 0..255
  int dir = bx >> 7;
  int b0 = (bx & 127) * MB4;
  int t = threadIdx.x;
  int w = t >> 6, lane = t & 63, l = lane & 15, q = lane >> 4;
  int bsel = l >> 2;            // batch whose h this lane's A-row carries

  __shared__ __align__(16) float table4[21 * 256];  // [tok+1][unit][gate-type]; 21.5 KB, doubles as staging
  __shared__ __align__(16) f16 hbuf[2][MB4][PAD];
  __shared__ short tok_s[SS * MB4];                 // [pos][m], stores tok+1
  __shared__ u64 red[256];
  __shared__ int mode_sh;

  // ---- mode probe: b_f read as bf16; fp32 shows wild exponents ----
  if (t == 0) mode_sh = 1;
  __syncthreads();
  {
    float v = bf2f(((const u16*)b_f)[t]);
    if (!(fabsf(v) < 1000.0f)) atomicAnd(&mode_sh, 0);
  }
  __syncthreads();
  int mode = mode_sh;
  const void* Wih = dir ? Wih_b : Wih_f;
  const void* Whh = dir ? Whh_b : Whh_f;
  const void* bv  = dir ? b_b   : b_f;

  // ---- token extraction for this block's 4 batches (staged through `table4` memory) ----
  u64 cnt = 0;  // packed 4x16-bit valid counts
  for (int m = 0; m < MB4; ++m) {
    if (mode) {
      u32* st = (u32*)table4;
      for (int k0 = 0; k0 < 4; ++k0) {
        const u32* src = (const u32*)in1 + ((size_t)(b0 + m) * SS + k0 * 256) * 10;
#pragma unroll
        for (int i = 0; i < 10; ++i) st[t + i * 256] = src[t + i * 256];  // coalesced
        __syncthreads();
        const u32* row = st + t * 10;
        int tok = -1;
#pragma unroll
        for (int ww = 0; ww < 10; ++ww) {
          u32 u = row[ww];
          if (u & 0xFFFFu) tok = 2 * ww;
          if (u >> 16)     tok = 2 * ww + 1;
        }
        tok_s[(k0 * 256 + t) * MB4 + m] = (short)(tok + 1);
        if (dir == 0) toks_g[(size_t)(b0 + m) * SS + k0 * 256 + t] = (short)tok;
        cnt += (u64)(tok >= 0) << (16 * m);
        __syncthreads();
      }
    } else {
      float4* st = (float4*)table4;
      for (int k0 = 0; k0 < 4; ++k0) {
        const float4* src = (const float4*)((const float*)in1 + ((size_t)(b0 + m) * SS + k0 * 256) * 20);
#pragma unroll
        for (int i = 0; i < 5; ++i) st[t + i * 256] = src[t + i * 256];  // coalesced 16B/lane
        __syncthreads();
        const float* row = (const float*)table4 + t * 20;
        int tok = -1;
#pragma unroll
        for (int ww = 0; ww < 20; ++ww)
          if (row[ww] != 0.f) tok = ww;
        tok_s[(k0 * 256 + t) * MB4 + m] = (short)(tok + 1);
        if (dir == 0) toks_g[(size_t)(b0 + m) * SS + k0 * 256 + t] = (short)tok;
        cnt += (u64)(tok >= 0) << (16 * m);
        __syncthreads();
      }
    }
  }
  // lens: packed u64 tree reduction (fwd blocks export)
  red[t] = cnt;
  __syncthreads();
  for (int stp = 128; stp > 0; stp >>= 1) {
    if (t < stp) red[t] += red[t + stp];
    __syncthreads();
  }
  if (dir == 0 && t < MB4)
    lens[b0 + t] = (int)((red[0] >> (16 * t)) & 0xFFFFull);
  __syncthreads();

  // ---- x-projection table: table4[r][u][tt] = scl_tt * (W_ih[64tt+u][r-1] + b[64tt+u]);
  //      row 0 = bias-only (padding). One float4 per (tok, unit) holds all 4 gate types.
  for (int idx = t; idx < 21 * 256; idx += 256) {
    int r = idx >> 8, g = idx & 255;     // g = 64*tt + u (source gate index)
    int tt = g >> 6, u = g & 63;
    float scl = (tt == 2) ? (2.f * LOG2E) : (-LOG2E);
    float v = ldw(bv, g, mode);
    if (r > 0) v += ldw(Wih, g * NI + (r - 1), mode);
    table4[r * 256 + u * 4 + tt] = scl * v;
  }
  // ---- W_hh B-fragments: n=lane&15 -> gate col (unit 16w+l, type tt), k=q*8+j ----
  f16x8 Bf[4][2];
#pragma unroll
  for (int tt = 0; tt < 4; ++tt) {
    float scl = (tt == 2) ? (2.f * LOG2E) : (-LOG2E);
    int g = 64 * tt + 16 * w + l;
#pragma unroll
    for (int kc = 0; kc < 2; ++kc) {
      f16x8 v;
#pragma unroll
      for (int j = 0; j < 8; ++j)
        v[j] = (f16)(scl * ldw(Whh, g * HH + kc * 32 + q * 8 + j, mode));
      Bf[tt][kc] = v;
    }
  }
  for (int idx = t; idx < 2 * MB4 * PAD; idx += 256)
    ((f16*)hbuf)[idx] = (f16)0.f;
  __syncthreads();

  float c_st = 0.f, hlast = 0.f;
  int jj = 16 * w + l;

  // x-pipeline prologue: wx for s=0 (regs), tok for s=1 (reg)
  f32x4 wxc;
  {
    int pos0 = dir ? (SS - 1) : 0;
    wxc = *(const f32x4*)&table4[(int)tok_s[pos0 * MB4 + q] * 256 + jj * 4];
  }
  int tok1;
  {
    int pos1 = dir ? (SS - 2) : 1;
    tok1 = (int)tok_s[pos1 * MB4 + q];
  }

#pragma unroll 2
  for (int s = 0; s < SS; ++s) {
    int p = s & 1;
    // critical path: h fragments (A[m=l][k=q*8+j] = h[bsel][k], 4x dup rows)
    f16x8 a0 = *(const f16x8*)&hbuf[p][bsel][q * 8];
    f16x8 a1 = *(const f16x8*)&hbuf[p][bsel][32 + q * 8];
    // off-path: wx prefetch for s+1 (one b128; tok1 from pipeline), tok fetch for s+2
    f32x4 wxn = *(const f32x4*)&table4[tok1 * 256 + jj * 4];
    {
      int pos2 = (dir ? (SS - 3 - s) : (s + 2)) & (SS - 1);  // wrapped values unused
      tok1 = (int)tok_s[pos2 * MB4 + q];
    }

    // r9-verified serial C-chain: C-init = x-projection, 2-deep MFMA per gate type
    f32x4 acc[4];
#pragma unroll
    for (int tt = 0; tt < 4; ++tt) {
      f32x4 ci = {wxc[tt], wxc[tt], wxc[tt], wxc[tt]};
      acc[tt] = __builtin_amdgcn_mfma_f32_16x16x32_f16(a0, Bf[tt][0], ci, 0, 0, 0);
    }
#pragma unroll
    for (int tt = 0; tt < 4; ++tt)
      acc[tt] = __builtin_amdgcn_mfma_f32_16x16x32_f16(a1, Bf[tt][1], acc[tt], 0, 0, 0);

    // activation (verified r6-r14; trans-pipe): Ei=e^-i, Ef=e^-f, Eo=e^-o, G=e^2g
    {
      float Ei = fexp2(acc[0][0]);
      float Ef = fexp2(acc[1][0]);
      float G  = fexp2(acc[2][0]);
      float Eo = fexp2(acc[3][0]);
      float Ei1 = Ei + 1.f, Ef1 = Ef + 1.f, G1 = G + 1.f, Gm = G - 1.f;
      float t1 = Ei1 * G1;
      float num = fmaf(c_st, t1, Gm * Ef1);
      float cv = num * frcp(t1 * Ef1);
      c_st = cv;
      float C = fexp2((2.f * LOG2E) * cv);
      float hv = (C - 1.f) * frcp((Eo + 1.f) * (C + 1.f));
      hlast = hv;
      hbuf[p ^ 1][q][jj] = (f16)hv;
    }
    __syncthreads();
    wxc = wxn;
  }
  hout[(b0 + q) * 128 + dir * 64 + jj] = hlast;
}

// ---- head, latency-optimized (r14-verified, ~22 us): 512 blocks x 256 thr ----
__global__ __launch_bounds__(256)
void head_kernel(const void* conv1_w, const void* conv2_w, const void* conv2_b,
                 const void* fc1_w, const void* fc1_b,
                 const void* fc2_w, const void* fc2_b,
                 const void* bvec, const short* toks, const int* lens,
                 const float* hout, void* out) {
  int b = blockIdx.x;
  int t = threadIdx.x;  // 256 threads
  __shared__ float c1w[400];
  __shared__ short tok_s[SS];
  __shared__ float pav[3][80];
  __shared__ float avg[80];
  __shared__ float cpart[2][100];
  __shared__ float merged[228];
  __shared__ float fpart[4][64];
  __shared__ float fc1v[64];
  __shared__ float f2p[2][64];
  __shared__ int mode_sh;

  if (t == 0) mode_sh = 1;
  __syncthreads();
  {
    float v = bf2f(((const u16*)bvec)[t]);
    if (!(fabsf(v) < 1000.0f)) atomicAnd(&mode_sh, 0);
  }
  __syncthreads();
  int mode = mode_sh;

  for (int i = t; i < 400; i += 256) c1w[i] = ldw(conv1_w, i, mode);
  for (int s = t; s < SS; s += 256) tok_s[s] = toks[(size_t)b * SS + s];
  __syncthreads();

  int len = lens[b];
  int bw = len >> 2;
  // ragged 4-bin mean: 240 threads = 80 (k,cc) units x 3 segments; 4 independent
  // partial-sum chains per thread so the tok->c1w dependent LDS reads pipeline.
  if (t < 240) {
    int seg = t / 80;
    int u = t - seg * 80;
    int k = u / 20, cc = u % 20;
    int base = k * bw;
    int s0 = base + (seg * bw) / 3;
    int s1 = base + ((seg + 1) * bw) / 3;
    float p0 = 0.f, p1 = 0.f, p2 = 0.f, p3 = 0.f;
    int s = s0;
    for (; s + 4 <= s1; s += 4) {
      // faithful torch reshape: flat f = s*20+cc of the [20,1024] map
      int f0 = s * 20 + cc, f1 = f0 + 20, f2 = f0 + 40, f3 = f0 + 60;
      int tk0 = tok_s[f0 & 1023];
      int tk1 = tok_s[f1 & 1023];
      int tk2 = tok_s[f2 & 1023];
      int tk3 = tok_s[f3 & 1023];
      if (tk0 >= 0) p0 += c1w[(f0 >> 10) * 20 + tk0];
      if (tk1 >= 0) p1 += c1w[(f1 >> 10) * 20 + tk1];
      if (tk2 >= 0) p2 += c1w[(f2 >> 10) * 20 + tk2];
      if (tk3 >= 0) p3 += c1w[(f3 >> 10) * 20 + tk3];
    }
    for (; s < s1; ++s) {
      int f = s * 20 + cc;
      int tk = tok_s[f & 1023];
      if (tk >= 0) p0 += c1w[(f >> 10) * 20 + tk];
    }
    pav[seg][u] = (p0 + p1) + (p2 + p3);
  }
  __syncthreads();
  if (t < 80) avg[t] = (pav[0][t] + pav[1][t] + pav[2][t]) / (float)bw;
  __syncthreads();

  // conv2: 200 threads = 100 outputs x 2 K-halves of 40, unroll 8
  if (t < 200) {
    int half = t / 100, o = t - half * 100;
    float dot = 0.f;
    int q0 = half * 40;
#pragma unroll 8
    for (int q = q0; q < q0 + 40; ++q)
      dot = fmaf(avg[q], ldw(conv2_w, o * 80 + q, mode), dot);
    cpart[half][o] = dot;
  }
  if (t < 128) merged[t] = hout[b * 128 + t];  // [h_fw | h_bw]
  __syncthreads();
  if (t < 100) {
    float dot = cpart[0][t] + cpart[1][t] + ldw(conv2_b, t, mode);
    merged[128 + t] = dot > 0.f ? dot : 0.f;  // relu
  }
  __syncthreads();

  // fc1: 256 threads = 64 outputs x 4 K-chunks of 57, unroll 8
  {
    int o = t & 63, ch = t >> 6;
    float v = 0.f;
    int m0 = ch * 57;
#pragma unroll 8
    for (int m = m0; m < m0 + 57; ++m)
      v = fmaf(merged[m], ldw(fc1_w, o * 228 + m, mode), v);
    fpart[ch][o] = v;
  }
  __syncthreads();
  if (t < 64)
    fc1v[t] = fpart[0][t] + fpart[1][t] + fpart[2][t] + fpart[3][t] + ldw(fc1_b, t, mode);
  __syncthreads();

  // fc2: 128 threads compute products, tree-reduce
  if (t < 128) {
    int o = t >> 6, m = t & 63;
    f2p[o][m] = fc1v[m] * ldw(fc2_w, o * 64 + m, mode);
  }
  __syncthreads();
  for (int stp = 32; stp > 0; stp >>= 1) {
    if (t < 128) {
      int o = t >> 6, m = t & 63;
      if (m < stp) f2p[o][m] += f2p[o][m + stp];
    }
    __syncthreads();
  }
  if (t == 0) {
    float x0 = f2p[0][0] + ldw(fc2_b, 0, mode);
    float x1 = f2p[1][0] + ldw(fc2_b, 1, mode);
    float mx = fmaxf(x0, x1);
    float e0 = fexp2(LOG2E * (x0 - mx)), e1 = fexp2(LOG2E * (x1 - mx));
    float inv = frcp(e0 + e1);
    if (mode) {
      ((__hip_bfloat16*)out)[b * 2 + 0] = __float2bfloat16(e0 * inv);
      ((__hip_bfloat16*)out)[b * 2 + 1] = __float2bfloat16(e1 * inv);
    } else {
      ((float*)out)[b * 2 + 0] = e0 * inv;
      ((float*)out)[b * 2 + 1] = e1 * inv;
    }
  }
}

extern "C" void kernel_launch(void* const* d_in, const int* in_sizes, int n_in,
                              void* d_out, int out_size, void* d_ws, size_t ws_size,
                              hipStream_t stream) {
  (void)in_sizes; (void)n_in; (void)out_size; (void)ws_size;
  char* ws = (char*)d_ws;
  int*   lens = (int*)(ws + 256);                             // 2 KB
  short* toks = (short*)(ws + 256 + 2048);                    // 1 MB
  float* hout = (float*)(ws + 256 + 2048 + (size_t)BB * SS * sizeof(short)); // 256 KB

  lstm_kernel<<<256, 256, 0, stream>>>(d_in[0],
                                       d_in[1], d_in[2], d_in[3],
                                       d_in[4], d_in[5], d_in[6],
                                       toks, lens, hout);
  head_kernel<<<BB, 256, 0, stream>>>(d_in[7], d_in[8], d_in[9],
                                      d_in[10], d_in[11], d_in[12], d_in[13],
                                      d_in[3], toks, lens, hout, d_out);
}